// Round 1
// baseline (164.941 us; speedup 1.0000x reference)
//
#include <hip/hip_runtime.h>
#include <math.h>

#define NSTUFF 6
#define NCLS   10          // N_STUFF + N_THING
#define NBOX   32
#define NTHING 4
#define RR     28
#define HH     768
#define WW     704
#define NPIX   (HH * WW)   // 540672
#define BB     2
#define LL     (1 + NSTUFF + NBOX)   // 39
#define NEGV   (-100.0f)

__device__ __forceinline__ float sigmoidf_(float x) {
    return 1.0f / (1.0f + expf(-x));
}

// ---------------------------------------------------------------------------
// K1: per-pixel fused logits + argmax + histograms.
// Writes po_pred (int32) into d_out's seam region; accumulates
// counts[B][32][10] (inst-pixel sem_pred histogram) and stuffh[B][6]
// (stuff-pixel po_pred histogram) via LDS-then-global atomics.
// ---------------------------------------------------------------------------
__global__ __launch_bounds__(256) void k_fuse(
    const float* __restrict__ sem,   // [B][10][H][W]
    const float* __restrict__ roi,   // [B][32][4][28][28]
    const float* __restrict__ bbx,   // [B][32][4]
    const int*   __restrict__ cls,   // [B][32]
    int*         __restrict__ pred,  // d_out seam region, [B][H][W]
    int*         __restrict__ counts,
    int*         __restrict__ stuffh)
{
    const int b = blockIdx.y;
    __shared__ int   sh_y0[NBOX], sh_x0[NBOX], sh_yme[NBOX], sh_xme[NBOX];
    __shared__ int   sh_yie[NBOX], sh_xie[NBOX], sh_moff[NBOX], sh_cls[NBOX];
    __shared__ float sh_y0f[NBOX], sh_x0f[NBOX], sh_sy[NBOX], sh_sx[NBOX];
    __shared__ int   sh_cnt[NBOX * NCLS + NSTUFF];

    const int t = threadIdx.x;
    for (int i = t; i < NBOX * NCLS + NSTUFF; i += blockDim.x) sh_cnt[i] = 0;
    if (t < NBOX) {
        const float* bbp = bbx + ((size_t)b * NBOX + t) * 4;
        float y0f = bbp[0], x0f = bbp[1], y1f = bbp[2], x1f = bbp[3];
        int y0 = (int)floorf(y0f), x0 = (int)floorf(x0f);
        int y1 = (int)floorf(y1f), x1 = (int)floorf(x1f);
        sh_y0[t] = y0;  sh_x0[t] = x0;
        sh_yme[t] = min(y1 + 1, HH);            // mask window end (clipped)
        sh_xme[t] = min(x1 + 1, WW);
        sh_yie[t] = (int)rintf(y1f) + 1;        // inst window end (round, unclipped)
        sh_xie[t] = (int)rintf(x1f) + 1;
        sh_y0f[t] = (float)y0; sh_x0f[t] = (float)x0;
        float hh = (float)max(y1 - y0 + 1, 1);
        float ww = (float)max(x1 - x0 + 1, 1);
        sh_sy[t] = 28.0f / hh;  sh_sx[t] = 28.0f / ww;
        int c = cls[b * NBOX + t];
        sh_cls[t] = c;
        sh_moff[t] = (((b * NBOX + t) * NTHING) + c) * (RR * RR);
    }
    __syncthreads();

    const float* semb = sem + (size_t)b * NCLS * NPIX;
    for (int p = blockIdx.x * blockDim.x + t; p < NPIX; p += gridDim.x * blockDim.x) {
        const int y = p / WW, x = p % WW;
        const float yf = (float)y, xf = (float)x;

        float s[NCLS];
        #pragma unroll
        for (int c = 0; c < NCLS; ++c) s[c] = semb[(size_t)c * NPIX + p];

        // sem_pred: argmax over 10 channels, first-occurrence ties
        float sb = s[0]; int sp = 0;
        #pragma unroll
        for (int c = 1; c < NCLS; ++c) if (s[c] > sb) { sb = s[c]; sp = c; }

        // po_pred: stuff channels 0..5 first
        float bv = s[0]; int bi = 0;
        #pragma unroll
        for (int c = 1; c < NSTUFF; ++c) if (s[c] > bv) { bv = s[c]; bi = c; }

        // then instance channels 6..37 (sequential, strict > keeps first max)
        for (int n = 0; n < NBOX; ++n) {
            const bool in_m = (y >= max(sh_y0[n], 0)) & (y < sh_yme[n]) &
                              (x >= max(sh_x0[n], 0)) & (x < sh_xme[n]);
            const bool in_i = (y >= sh_y0[n]) & (y < sh_yie[n]) &
                              (x >= sh_x0[n]) & (x < sh_xie[n]);
            float v;
            if (in_m | in_i) {
                float pm = NEGV;
                if (in_m) {
                    // sy = clip(((yf - y0) + 0.5)*(28/h) - 0.5, 0, 27) — exact ref op order
                    float sy = __fsub_rn(__fmul_rn(__fadd_rn(__fsub_rn(yf, sh_y0f[n]), 0.5f), sh_sy[n]), 0.5f);
                    sy = fminf(fmaxf(sy, 0.0f), 27.0f);
                    int ylo = (int)sy;                   // floor (sy >= 0)
                    int yhi = min(ylo + 1, RR - 1);
                    float wy = __fsub_rn(sy, (float)ylo);
                    float sx = __fsub_rn(__fmul_rn(__fadd_rn(__fsub_rn(xf, sh_x0f[n]), 0.5f), sh_sx[n]), 0.5f);
                    sx = fminf(fmaxf(sx, 0.0f), 27.0f);
                    int xlo = (int)sx;
                    int xhi = min(xlo + 1, RR - 1);
                    float wx = __fsub_rn(sx, (float)xlo);
                    const float* m = roi + sh_moff[n];
                    float m00 = m[ylo * RR + xlo], m01 = m[ylo * RR + xhi];
                    float m10 = m[yhi * RR + xlo], m11 = m[yhi * RR + xhi];
                    float omy = __fsub_rn(1.0f, wy), omx = __fsub_rn(1.0f, wx);
                    float rl = __fadd_rn(__fmul_rn(m00, omy), __fmul_rn(m10, wy));
                    float rh = __fadd_rn(__fmul_rn(m01, omy), __fmul_rn(m11, wy));
                    pm = __fadd_rn(__fmul_rn(rl, omx), __fmul_rn(rh, wx));
                }
                float pi = NEGV;
                if (in_i) {
                    int c = sh_cls[n];
                    pi = (c == 0) ? s[6] : (c == 1) ? s[7] : (c == 2) ? s[8] : s[9];
                }
                v = __fmul_rn(__fadd_rn(sigmoidf_(pi), sigmoidf_(pm)), __fadd_rn(pi, pm));
            } else {
                v = -0.0f;   // (sig(-100)+sig(-100))*(-200) == -0.0f exactly in fp32
            }
            if (v > bv) { bv = v; bi = NSTUFF + n; }
        }

        pred[(size_t)b * NPIX + p] = bi;
        if (bi < NSTUFF) atomicAdd(&sh_cnt[NBOX * NCLS + bi], 1);
        else             atomicAdd(&sh_cnt[(bi - NSTUFF) * NCLS + sp], 1);
    }
    __syncthreads();
    for (int i = t; i < NBOX * NCLS + NSTUFF; i += blockDim.x) {
        int v = sh_cnt[i];
        if (v) {
            if (i < NBOX * NCLS) atomicAdd(&counts[b * NBOX * NCLS + i], v);
            else                 atomicAdd(&stuffh[b * NSTUFF + (i - NBOX * NCLS)], v);
        }
    }
}

// ---------------------------------------------------------------------------
// K2: per-batch relabel logic (tiny). Thread 0 of each of 2 blocks does a
// batch serially. Derives ih/sh analytically from counts; writes the seam
// LUT (ws), po_cls and po_iscrowd regions of d_out.
// ---------------------------------------------------------------------------
__global__ void k_label(const int* __restrict__ counts,
                        const int* __restrict__ stuffh,
                        const int* __restrict__ cls,
                        int*       __restrict__ out,
                        int*       __restrict__ lut)
{
    const int b = blockIdx.x;
    if (threadIdx.x != 0) return;
    const int* C = counts + b * NBOX * NCLS;

    int summ[NBOX], majv[NBOX], idxA[NBOX], semv[NBOX];
    bool pres[NBOX], tost[NBOX];
    int run = -1;
    for (int n = 0; n < NBOX; ++n) {
        int m = C[n * NCLS]; int mj = 0; int ssum = m;
        for (int c = 1; c < NCLS; ++c) {
            int v = C[n * NCLS + c];
            ssum += v;
            if (v > m) { m = v; mj = c; }      // first-occurrence argmax
        }
        bool pr = ssum > 0;
        if (pr) run++;
        idxA[n] = run;                          // cumsum(present)-1
        int thing = cls[b * NBOX + n] + NSTUFF;
        // frac >= 0.5  <=>  2*max >= sum (exact; fp32 division can't cross 0.5 here)
        bool ts = pr && (mj != thing) && (2 * m >= ssum) && (mj < NSTUFF);
        summ[n] = ssum; majv[n] = mj; pres[n] = pr; tost[n] = ts;
        semv[n] = ts ? mj : thing;
    }

    // sh: stuff-pixel histogram + pixels of to_stuff instances
    int sh[NSTUFF];
    for (int s = 0; s < NSTUFF; ++s) sh[s] = stuffh[b * NSTUFF + s];
    for (int n = 0; n < NBOX; ++n) if (pres[n] && tost[n]) sh[majv[n]] += summ[n];
    int srank[NSTUFF]; int r2 = -1;
    for (int s = 0; s < NSTUFF; ++s) { if (sh[s] > 0) r2++; srank[s] = r2; }
    const int nst = r2 + 1;

    // ih: pixels per compacted instance slot
    int ih[NBOX];
    for (int j = 0; j < NBOX; ++j) ih[j] = 0;
    for (int n = 0; n < NBOX; ++n) if (pres[n] && !tost[n]) ih[idxA[n]] += summ[n];
    int irank[NBOX]; int r3 = -1;
    for (int j = 0; j < NBOX; ++j) { if (ih[j] > 0) r3++; irank[j] = r3; }

    // seam LUT over po_pred values [0,38)
    int* lb = lut + b * (NSTUFF + NBOX);
    for (int s = 0; s < NSTUFF; ++s) lb[s] = 1 + srank[s];
    for (int n = 0; n < NBOX; ++n) {
        int q = idxA[n] < 0 ? 0 : idxA[n];
        lb[NSTUFF + n] = tost[n] ? (1 + srank[majv[n]]) : (1 + nst + irank[q]);
    }

    // cls_out
    int co[LL];
    for (int i = 0; i < LL; ++i) co[i] = 255;
    for (int s = 0; s < NSTUFF; ++s) if (sh[s] > 0) co[1 + srank[s]] = s;
    int inst_sem[NBOX];
    for (int j = 0; j < NBOX; ++j) inst_sem[j] = 255;
    for (int n = 0; n < NBOX; ++n) if (pres[n] && !tost[n]) inst_sem[idxA[n]] = semv[n];
    for (int j = 0; j < NBOX; ++j) if (ih[j] > 0) co[1 + nst + irank[j]] = inst_sem[j];

    int* ocls = out + (size_t)BB * NPIX + b * LL;
    for (int i = 0; i < LL; ++i) ocls[i] = co[i];
    int* ocrd = out + (size_t)BB * NPIX + BB * LL + b * LL;
    for (int i = 0; i < LL; ++i) ocrd[i] = 0;
}

// ---------------------------------------------------------------------------
// K3: in-place po_pred -> seam via LUT.
// ---------------------------------------------------------------------------
__global__ __launch_bounds__(256) void k_seam(int* __restrict__ out,
                                              const int* __restrict__ lut)
{
    __shared__ int slut[BB * (NSTUFF + NBOX)];
    for (int i = threadIdx.x; i < BB * (NSTUFF + NBOX); i += blockDim.x)
        slut[i] = lut[i];
    __syncthreads();
    size_t p = (size_t)blockIdx.x * blockDim.x + threadIdx.x;   // grid sized exactly
    int pp = out[p];
    int b = (p >= (size_t)NPIX) ? 1 : 0;
    out[p] = slut[b * (NSTUFF + NBOX) + pp];
}

extern "C" void kernel_launch(void* const* d_in, const int* in_sizes, int n_in,
                              void* d_out, int out_size, void* d_ws, size_t ws_size,
                              hipStream_t stream) {
    (void)in_sizes; (void)n_in; (void)out_size; (void)ws_size;
    const float* sem = (const float*)d_in[0];
    const float* roi = (const float*)d_in[1];
    const float* bbx = (const float*)d_in[2];
    const int*   cls = (const int*)d_in[3];
    int* out = (int*)d_out;

    int* counts = (int*)d_ws;                        // [B][32][10]
    int* stuffh = counts + BB * NBOX * NCLS;         // [B][6]
    int* lut    = stuffh + BB * NSTUFF;              // [B][38]

    hipMemsetAsync(d_ws, 0, (BB * NBOX * NCLS + BB * NSTUFF) * sizeof(int), stream);

    dim3 g1(512, BB);
    k_fuse<<<g1, 256, 0, stream>>>(sem, roi, bbx, cls, out, counts, stuffh);
    k_label<<<BB, 64, 0, stream>>>(counts, stuffh, cls, out, lut);
    k_seam<<<(BB * NPIX) / 256, 256, 0, stream>>>(out, lut);
}

// Round 2
// 155.884 us; speedup vs baseline: 1.0581x; 1.0581x over previous
//
#include <hip/hip_runtime.h>
#include <math.h>

#define NSTUFF 6
#define NCLS   10          // N_STUFF + N_THING
#define NBOX   32
#define NTHING 4
#define RR     28
#define HH     768
#define WW     704
#define NPIX   (HH * WW)   // 540672
#define BB     2
#define LL     (1 + NSTUFF + NBOX)   // 39
#define NEGV   (-100.0f)

#define TW 64
#define TH 4
#define TILES_X (WW / TW)            // 11
#define TILES_Y (HH / TH)            // 192
#define NTILES  (TILES_X * TILES_Y)  // 2112

__device__ __forceinline__ float sigmoidf_(float x) {
    return 1.0f / (1.0f + expf(-x));
}

// ---------------------------------------------------------------------------
// K1: tiled per-pixel fused logits + argmax + histograms, with per-tile box
// culling. Sequential-argmax semantics preserved via the "gap" rule: any
// skipped box contributes exactly -0.0f, and within a run of skipped boxes
// only the first can win, and only while bv < 0.
// ---------------------------------------------------------------------------
__global__ __launch_bounds__(256) void k_fuse(
    const float* __restrict__ sem,   // [B][10][H][W]
    const float* __restrict__ roi,   // [B][32][4][28][28]
    const float* __restrict__ bbx,   // [B][32][4]
    const int*   __restrict__ cls,   // [B][32]
    int*         __restrict__ pred,  // d_out seam region, [B][H][W]
    int*         __restrict__ counts,
    int*         __restrict__ stuffh)
{
    const int b = blockIdx.y;
    __shared__ int   sh_y0[NBOX], sh_x0[NBOX], sh_yme[NBOX], sh_xme[NBOX];
    __shared__ int   sh_yie[NBOX], sh_xie[NBOX], sh_uy[NBOX], sh_ux[NBOX];
    __shared__ int   sh_moff[NBOX], sh_cls[NBOX];
    __shared__ float sh_y0f[NBOX], sh_x0f[NBOX], sh_sy[NBOX], sh_sx[NBOX];
    __shared__ int   sh_list[NBOX];
    __shared__ int   sh_nbox;
    __shared__ int   sh_cnt[NBOX * NCLS + NSTUFF];

    const int t = threadIdx.x;
    const int tile = blockIdx.x;
    const int tx0 = (tile % TILES_X) * TW;
    const int ty0 = (tile / TILES_X) * TH;

    for (int i = t; i < NBOX * NCLS + NSTUFF; i += blockDim.x) sh_cnt[i] = 0;
    if (t < NBOX) {
        const float* bbp = bbx + ((size_t)b * NBOX + t) * 4;
        float y0f = bbp[0], x0f = bbp[1], y1f = bbp[2], x1f = bbp[3];
        int y0 = (int)floorf(y0f), x0 = (int)floorf(x0f);
        int y1 = (int)floorf(y1f), x1 = (int)floorf(x1f);
        int yme = min(y1 + 1, HH), xme = min(x1 + 1, WW);
        int yie = (int)rintf(y1f) + 1, xie = (int)rintf(x1f) + 1;
        sh_y0[t] = y0;  sh_x0[t] = x0;
        sh_yme[t] = yme; sh_xme[t] = xme;
        sh_yie[t] = yie; sh_xie[t] = xie;
        sh_uy[t] = max(yme, yie); sh_ux[t] = max(xme, xie);
        sh_y0f[t] = (float)y0; sh_x0f[t] = (float)x0;
        float hh = (float)max(y1 - y0 + 1, 1);
        float ww = (float)max(x1 - x0 + 1, 1);
        sh_sy[t] = 28.0f / hh;  sh_sx[t] = 28.0f / ww;
        int c = cls[b * NBOX + t];
        sh_cls[t] = c;
        sh_moff[t] = (((b * NBOX + t) * NTHING) + c) * (RR * RR);
    }
    __syncthreads();

    // per-tile box culling (wave 0 only does the writes; t<32 is one wave)
    {
        bool flag = false;
        if (t < NBOX)
            flag = (sh_y0[t] < ty0 + TH) && (sh_uy[t] > ty0) &&
                   (sh_x0[t] < tx0 + TW) && (sh_ux[t] > tx0);
        unsigned long long m = __ballot(flag);
        if (t < NBOX && flag) {
            int pos = __popcll(m & (((unsigned long long)1 << t) - 1ull));
            sh_list[pos] = t;
        }
        if (t == 0) sh_nbox = __popcll(m);
    }
    __syncthreads();

    const float* semb = sem + (size_t)b * NCLS * NPIX;
    const int x = tx0 + (t & (TW - 1));
    const int y = ty0 + (t >> 6);
    const int p = y * WW + x;
    const float yf = (float)y, xf = (float)x;

    float s[NCLS];
    #pragma unroll
    for (int c = 0; c < NSTUFF; ++c) s[c] = semb[(size_t)c * NPIX + p];

    // stuff argmax first
    float bv = s[0]; int bi = 0;
    #pragma unroll
    for (int c = 1; c < NSTUFF; ++c) if (s[c] > bv) { bv = s[c]; bi = c; }

    const int nb = sh_nbox;
    int sp = 0;
    if ((nb > 0) || (bv < 0.0f)) {
        #pragma unroll
        for (int c = NSTUFF; c < NCLS; ++c) s[c] = semb[(size_t)c * NPIX + p];

        // sem_pred: full 10-channel argmax, first-occurrence ties
        float sb = s[0];
        #pragma unroll
        for (int c = 1; c < NCLS; ++c) if (s[c] > sb) { sb = s[c]; sp = c; }

        int prev = -1;
        for (int j = 0; j < nb; ++j) {
            const int n = sh_list[j];
            if (n > prev + 1 && bv < 0.0f) { bv = -0.0f; bi = NSTUFF + prev + 1; }
            const bool in_m = (y >= max(sh_y0[n], 0)) & (y < sh_yme[n]) &
                              (x >= max(sh_x0[n], 0)) & (x < sh_xme[n]);
            const bool in_i = (y >= sh_y0[n]) & (y < sh_yie[n]) &
                              (x >= sh_x0[n]) & (x < sh_xie[n]);
            float v;
            if (in_m | in_i) {
                float pm = NEGV;
                if (in_m) {
                    float sy = __fsub_rn(__fmul_rn(__fadd_rn(__fsub_rn(yf, sh_y0f[n]), 0.5f), sh_sy[n]), 0.5f);
                    sy = fminf(fmaxf(sy, 0.0f), 27.0f);
                    int ylo = (int)sy;
                    int yhi = min(ylo + 1, RR - 1);
                    float wy = __fsub_rn(sy, (float)ylo);
                    float sx = __fsub_rn(__fmul_rn(__fadd_rn(__fsub_rn(xf, sh_x0f[n]), 0.5f), sh_sx[n]), 0.5f);
                    sx = fminf(fmaxf(sx, 0.0f), 27.0f);
                    int xlo = (int)sx;
                    int xhi = min(xlo + 1, RR - 1);
                    float wx = __fsub_rn(sx, (float)xlo);
                    const float* m = roi + sh_moff[n];
                    float m00 = m[ylo * RR + xlo], m01 = m[ylo * RR + xhi];
                    float m10 = m[yhi * RR + xlo], m11 = m[yhi * RR + xhi];
                    float omy = __fsub_rn(1.0f, wy), omx = __fsub_rn(1.0f, wx);
                    float rl = __fadd_rn(__fmul_rn(m00, omy), __fmul_rn(m10, wy));
                    float rh = __fadd_rn(__fmul_rn(m01, omy), __fmul_rn(m11, wy));
                    pm = __fadd_rn(__fmul_rn(rl, omx), __fmul_rn(rh, wx));
                }
                float pi = NEGV;
                if (in_i) {
                    int c = sh_cls[n];
                    pi = (c == 0) ? s[6] : (c == 1) ? s[7] : (c == 2) ? s[8] : s[9];
                }
                v = __fmul_rn(__fadd_rn(sigmoidf_(pi), sigmoidf_(pm)), __fadd_rn(pi, pm));
            } else {
                v = -0.0f;
            }
            if (v > bv) { bv = v; bi = NSTUFF + n; }
            prev = n;
        }
        if (prev < NBOX - 1 && bv < 0.0f) { bv = -0.0f; bi = NSTUFF + prev + 1; }
    }

    pred[(size_t)b * NPIX + p] = bi;
    if (bi < NSTUFF) atomicAdd(&sh_cnt[NBOX * NCLS + bi], 1);
    else             atomicAdd(&sh_cnt[(bi - NSTUFF) * NCLS + sp], 1);

    __syncthreads();
    for (int i = t; i < NBOX * NCLS + NSTUFF; i += blockDim.x) {
        int v = sh_cnt[i];
        if (v) {
            if (i < NBOX * NCLS) atomicAdd(&counts[b * NBOX * NCLS + i], v);
            else                 atomicAdd(&stuffh[b * NSTUFF + (i - NBOX * NCLS)], v);
        }
    }
}

// ---------------------------------------------------------------------------
// K2: per-batch relabel. Parallel per-box phase (32 threads, one latency
// round), ballot prefix for idx, then a short thread-0 serial tail on LDS.
// ---------------------------------------------------------------------------
__global__ __launch_bounds__(64) void k_label(
    const int* __restrict__ counts,
    const int* __restrict__ stuffh,
    const int* __restrict__ cls,
    int*       __restrict__ out,
    int*       __restrict__ lut)
{
    const int b = blockIdx.x;
    const int t = threadIdx.x;
    __shared__ int s_summ[NBOX], s_maj[NBOX], s_idx[NBOX], s_sem[NBOX];
    __shared__ int s_pres[NBOX], s_tost[NBOX];
    __shared__ int s_sh[NSTUFF];

    if (t < NSTUFF) s_sh[t] = stuffh[b * NSTUFF + t];
    bool pr = false;
    if (t < NBOX) {
        const int* C = counts + ((size_t)b * NBOX + t) * NCLS;
        int c[NCLS];
        #pragma unroll
        for (int i = 0; i < NCLS; ++i) c[i] = C[i];
        int m = c[0], mj = 0, ssum = c[0];
        #pragma unroll
        for (int i = 1; i < NCLS; ++i) {
            ssum += c[i];
            if (c[i] > m) { m = c[i]; mj = i; }
        }
        pr = ssum > 0;
        int thing = cls[b * NBOX + t] + NSTUFF;
        bool ts = pr && (mj != thing) && (2 * m >= ssum) && (mj < NSTUFF);
        s_summ[t] = ssum; s_maj[t] = mj; s_pres[t] = pr ? 1 : 0;
        s_tost[t] = ts ? 1 : 0; s_sem[t] = ts ? mj : thing;
    }
    unsigned long long pm = __ballot(pr);
    if (t < NBOX)
        s_idx[t] = __popcll(pm & (((unsigned long long)2 << t) - 1ull)) - 1;
    __syncthreads();

    if (t != 0) return;

    // stuff histogram including to_stuff instance pixels
    int sh[NSTUFF];
    for (int s = 0; s < NSTUFF; ++s) sh[s] = s_sh[s];
    for (int n = 0; n < NBOX; ++n)
        if (s_pres[n] && s_tost[n]) sh[s_maj[n]] += s_summ[n];
    int srank[NSTUFF]; int r2 = -1;
    for (int s = 0; s < NSTUFF; ++s) { if (sh[s] > 0) r2++; srank[s] = r2; }
    const int nst = r2 + 1;

    int ih[NBOX];
    for (int j = 0; j < NBOX; ++j) ih[j] = 0;
    for (int n = 0; n < NBOX; ++n)
        if (s_pres[n] && !s_tost[n]) ih[s_idx[n]] += s_summ[n];
    int irank[NBOX]; int r3 = -1;
    for (int j = 0; j < NBOX; ++j) { if (ih[j] > 0) r3++; irank[j] = r3; }

    int* lb = lut + b * (NSTUFF + NBOX);
    for (int s = 0; s < NSTUFF; ++s) lb[s] = 1 + srank[s];
    for (int n = 0; n < NBOX; ++n) {
        int q = s_idx[n] < 0 ? 0 : s_idx[n];
        lb[NSTUFF + n] = s_tost[n] ? (1 + srank[s_maj[n]]) : (1 + nst + irank[q]);
    }

    int co[LL];
    for (int i = 0; i < LL; ++i) co[i] = 255;
    for (int s = 0; s < NSTUFF; ++s) if (sh[s] > 0) co[1 + srank[s]] = s;
    int inst_sem[NBOX];
    for (int j = 0; j < NBOX; ++j) inst_sem[j] = 255;
    for (int n = 0; n < NBOX; ++n)
        if (s_pres[n] && !s_tost[n]) inst_sem[s_idx[n]] = s_sem[n];
    for (int j = 0; j < NBOX; ++j) if (ih[j] > 0) co[1 + nst + irank[j]] = inst_sem[j];

    int* ocls = out + (size_t)BB * NPIX + b * LL;
    for (int i = 0; i < LL; ++i) ocls[i] = co[i];
    int* ocrd = out + (size_t)BB * NPIX + BB * LL + b * LL;
    for (int i = 0; i < LL; ++i) ocrd[i] = 0;
}

// ---------------------------------------------------------------------------
// K3: in-place po_pred -> seam via LUT.
// ---------------------------------------------------------------------------
__global__ __launch_bounds__(256) void k_seam(int* __restrict__ out,
                                              const int* __restrict__ lut)
{
    __shared__ int slut[BB * (NSTUFF + NBOX)];
    for (int i = threadIdx.x; i < BB * (NSTUFF + NBOX); i += blockDim.x)
        slut[i] = lut[i];
    __syncthreads();
    size_t p = (size_t)blockIdx.x * blockDim.x + threadIdx.x;
    int pp = out[p];
    int b = (p >= (size_t)NPIX) ? 1 : 0;
    out[p] = slut[b * (NSTUFF + NBOX) + pp];
}

extern "C" void kernel_launch(void* const* d_in, const int* in_sizes, int n_in,
                              void* d_out, int out_size, void* d_ws, size_t ws_size,
                              hipStream_t stream) {
    (void)in_sizes; (void)n_in; (void)out_size; (void)ws_size;
    const float* sem = (const float*)d_in[0];
    const float* roi = (const float*)d_in[1];
    const float* bbx = (const float*)d_in[2];
    const int*   cls = (const int*)d_in[3];
    int* out = (int*)d_out;

    int* counts = (int*)d_ws;                        // [B][32][10]
    int* stuffh = counts + BB * NBOX * NCLS;         // [B][6]
    int* lut    = stuffh + BB * NSTUFF;              // [B][38]

    hipMemsetAsync(d_ws, 0, (BB * NBOX * NCLS + BB * NSTUFF) * sizeof(int), stream);

    dim3 g1(NTILES, BB);
    k_fuse<<<g1, 256, 0, stream>>>(sem, roi, bbx, cls, out, counts, stuffh);
    k_label<<<BB, 64, 0, stream>>>(counts, stuffh, cls, out, lut);
    k_seam<<<(BB * NPIX) / 256, 256, 0, stream>>>(out, lut);
}

// Round 3
// 118.769 us; speedup vs baseline: 1.3888x; 1.3125x over previous
//
#include <hip/hip_runtime.h>
#include <math.h>

#define NSTUFF 6
#define NCLS   10          // N_STUFF + N_THING
#define NBOX   32
#define NTHING 4
#define RR     28
#define HH     768
#define WW     704
#define NPIX   (HH * WW)   // 540672
#define BB     2
#define LL     (1 + NSTUFF + NBOX)   // 39
#define NEGV   (-100.0f)

#define TW 64
#define TH 8
#define TILES_X (WW / TW)            // 11
#define TILES_Y (HH / TH)            // 96
#define NTILES  (TILES_X * TILES_Y)  // 1056

__device__ __forceinline__ float sigmoidf_(float x) {
    return 1.0f / (1.0f + expf(-x));
}

// ---------------------------------------------------------------------------
// K1: tiled fused logits + argmax + histograms. 2 pixels/thread, all 20 sem
// loads issued upfront (independent -> one latency round). Per-tile box cull
// done in-register by wave 0. Sequential-argmax semantics preserved via the
// gap rule (skipped boxes contribute exactly -0.0f; only the first skipped
// box can win, and only while bv < 0).
// ---------------------------------------------------------------------------
__global__ __launch_bounds__(256) void k_fuse(
    const float* __restrict__ sem,   // [B][10][H][W]
    const float* __restrict__ roi,   // [B][32][4][28][28]
    const float* __restrict__ bbx,   // [B][32][4]
    const int*   __restrict__ cls,   // [B][32]
    int*         __restrict__ pred,  // d_out seam region, [B][H][W]
    int*         __restrict__ counts,
    int*         __restrict__ stuffh)
{
    const int b = blockIdx.y;
    __shared__ int   sh_y0[NBOX], sh_x0[NBOX], sh_yme[NBOX], sh_xme[NBOX];
    __shared__ int   sh_yie[NBOX], sh_xie[NBOX], sh_moff[NBOX], sh_cls[NBOX];
    __shared__ float sh_y0f[NBOX], sh_x0f[NBOX], sh_sy[NBOX], sh_sx[NBOX];
    __shared__ int   sh_list[NBOX];
    __shared__ int   sh_nbox;
    __shared__ int   sh_cnt[NBOX * NCLS + NSTUFF];

    const int t = threadIdx.x;
    const int tile = blockIdx.x;
    const int tx0 = (tile % TILES_X) * TW;
    const int ty0 = (tile / TILES_X) * TH;

    const int x  = tx0 + (t & (TW - 1));
    const int yA = ty0 + (t >> 6);          // rows 0..3 of tile
    const int yB = yA + 4;                  // rows 4..7 of tile
    const int pA = yA * WW + x;
    const int pB = yB * WW + x;

    // Issue all 20 sem loads upfront (independent).
    const float* semb = sem + (size_t)b * NCLS * NPIX;
    float s0[NCLS], s1[NCLS];
    #pragma unroll
    for (int c = 0; c < NCLS; ++c) s0[c] = semb[(size_t)c * NPIX + pA];
    #pragma unroll
    for (int c = 0; c < NCLS; ++c) s1[c] = semb[(size_t)c * NPIX + pB];

    for (int i = t; i < NBOX * NCLS + NSTUFF; i += blockDim.x) sh_cnt[i] = 0;

    // wave 0: per-box setup + in-register tile cull (no extra barrier)
    if (t < 64) {
        bool flag = false;
        if (t < NBOX) {
            const float* bbp = bbx + ((size_t)b * NBOX + t) * 4;
            float y0f = bbp[0], x0f = bbp[1], y1f = bbp[2], x1f = bbp[3];
            int y0 = (int)floorf(y0f), x0 = (int)floorf(x0f);
            int y1 = (int)floorf(y1f), x1 = (int)floorf(x1f);
            int yme = min(y1 + 1, HH), xme = min(x1 + 1, WW);
            int yie = (int)rintf(y1f) + 1, xie = (int)rintf(x1f) + 1;
            sh_y0[t] = y0;  sh_x0[t] = x0;
            sh_yme[t] = yme; sh_xme[t] = xme;
            sh_yie[t] = yie; sh_xie[t] = xie;
            sh_y0f[t] = (float)y0; sh_x0f[t] = (float)x0;
            float hh = (float)max(y1 - y0 + 1, 1);
            float ww = (float)max(x1 - x0 + 1, 1);
            sh_sy[t] = 28.0f / hh;  sh_sx[t] = 28.0f / ww;
            int c = cls[b * NBOX + t];
            sh_cls[t] = c;
            sh_moff[t] = (((b * NBOX + t) * NTHING) + c) * (RR * RR);
            int uy = max(yme, yie), ux = max(xme, xie);
            flag = (y0 < ty0 + TH) && (uy > ty0) && (x0 < tx0 + TW) && (ux > tx0);
        }
        unsigned long long m = __ballot(flag);
        if (flag) {
            int pos = __popcll(m & (((unsigned long long)1 << t) - 1ull));
            sh_list[pos] = t;
        }
        if (t == 0) sh_nbox = __popcll(m);
    }
    __syncthreads();

    const int nb = sh_nbox;

    auto doPix = [&](const float* s, int y, int x_, float yf, float xf,
                     int& bi_o, int& sp_o) {
        // sem_pred: full 10-channel argmax, first-occurrence ties
        float sb = s[0]; int sp = 0;
        #pragma unroll
        for (int c = 1; c < NCLS; ++c) if (s[c] > sb) { sb = s[c]; sp = c; }

        // stuff argmax
        float bv = s[0]; int bi = 0;
        #pragma unroll
        for (int c = 1; c < NSTUFF; ++c) if (s[c] > bv) { bv = s[c]; bi = c; }

        int prev = -1;
        for (int j = 0; j < nb; ++j) {
            const int n = sh_list[j];
            if (n > prev + 1 && bv < 0.0f) { bv = -0.0f; bi = NSTUFF + prev + 1; }
            const bool in_m = (y >= max(sh_y0[n], 0)) & (y < sh_yme[n]) &
                              (x_ >= max(sh_x0[n], 0)) & (x_ < sh_xme[n]);
            const bool in_i = (y >= sh_y0[n]) & (y < sh_yie[n]) &
                              (x_ >= sh_x0[n]) & (x_ < sh_xie[n]);
            float v;
            if (in_m | in_i) {
                float pm = NEGV;
                if (in_m) {
                    float sy = __fsub_rn(__fmul_rn(__fadd_rn(__fsub_rn(yf, sh_y0f[n]), 0.5f), sh_sy[n]), 0.5f);
                    sy = fminf(fmaxf(sy, 0.0f), 27.0f);
                    int ylo = (int)sy;
                    int yhi = min(ylo + 1, RR - 1);
                    float wy = __fsub_rn(sy, (float)ylo);
                    float sx = __fsub_rn(__fmul_rn(__fadd_rn(__fsub_rn(xf, sh_x0f[n]), 0.5f), sh_sx[n]), 0.5f);
                    sx = fminf(fmaxf(sx, 0.0f), 27.0f);
                    int xlo = (int)sx;
                    int xhi = min(xlo + 1, RR - 1);
                    float wx = __fsub_rn(sx, (float)xlo);
                    const float* m = roi + sh_moff[n];
                    float m00 = m[ylo * RR + xlo], m01 = m[ylo * RR + xhi];
                    float m10 = m[yhi * RR + xlo], m11 = m[yhi * RR + xhi];
                    float omy = __fsub_rn(1.0f, wy), omx = __fsub_rn(1.0f, wx);
                    float rl = __fadd_rn(__fmul_rn(m00, omy), __fmul_rn(m10, wy));
                    float rh = __fadd_rn(__fmul_rn(m01, omy), __fmul_rn(m11, wy));
                    pm = __fadd_rn(__fmul_rn(rl, omx), __fmul_rn(rh, wx));
                }
                float pi = NEGV;
                if (in_i) {
                    int c = sh_cls[n];
                    pi = (c == 0) ? s[6] : (c == 1) ? s[7] : (c == 2) ? s[8] : s[9];
                }
                v = __fmul_rn(__fadd_rn(sigmoidf_(pi), sigmoidf_(pm)), __fadd_rn(pi, pm));
            } else {
                v = -0.0f;
            }
            if (v > bv) { bv = v; bi = NSTUFF + n; }
            prev = n;
        }
        if (prev < NBOX - 1 && bv < 0.0f) { bi = NSTUFF + prev + 1; }
        bi_o = bi; sp_o = sp;
    };

    int biA, spA, biB, spB;
    doPix(s0, yA, x, (float)yA, (float)x, biA, spA);
    doPix(s1, yB, x, (float)yB, (float)x, biB, spB);

    pred[(size_t)b * NPIX + pA] = biA;
    pred[(size_t)b * NPIX + pB] = biB;

    // histogram: ballot-aggregate the (dominant) stuff bins; scatter the rest
    const int lane = t & 63;
    #pragma unroll
    for (int s = 0; s < NSTUFF; ++s) {
        unsigned long long mA = __ballot(biA == s);
        unsigned long long mB = __ballot(biB == s);
        int c = __popcll(mA) + __popcll(mB);
        if (lane == 0 && c) atomicAdd(&sh_cnt[NBOX * NCLS + s], c);
    }
    if (biA >= NSTUFF) atomicAdd(&sh_cnt[(biA - NSTUFF) * NCLS + spA], 1);
    if (biB >= NSTUFF) atomicAdd(&sh_cnt[(biB - NSTUFF) * NCLS + spB], 1);

    __syncthreads();
    for (int i = t; i < NBOX * NCLS + NSTUFF; i += blockDim.x) {
        int v = sh_cnt[i];
        if (v) {
            if (i < NBOX * NCLS) atomicAdd(&counts[b * NBOX * NCLS + i], v);
            else                 atomicAdd(&stuffh[b * NSTUFF + (i - NBOX * NCLS)], v);
        }
    }
}

// ---------------------------------------------------------------------------
// K2: per-batch relabel, single wave, fully parallel. Ranks are pure
// functions of ballot masks (srank(c) = popcll(mask & ((2<<c)-1)) - 1), so
// there is no serial tail and no cross-lane reads.
// ---------------------------------------------------------------------------
__global__ __launch_bounds__(64) void k_label(
    const int* __restrict__ counts,
    const int* __restrict__ stuffh,
    const int* __restrict__ cls,
    int*       __restrict__ out,
    int*       __restrict__ lut)
{
    const int b = blockIdx.x;
    const int t = threadIdx.x;
    __shared__ int l_sh[NSTUFF];
    __shared__ int l_ih[NBOX];
    __shared__ int l_isem[NBOX];
    __shared__ int l_co[LL];

    if (t < NSTUFF) l_sh[t] = stuffh[b * NSTUFF + t];
    if (t < NBOX)  { l_ih[t] = 0; l_isem[t] = 255; }
    if (t < LL)      l_co[t] = 255;

    int  ssum = 0, mj = 0, semv = 0, idx = -1;
    bool pres = false, ts = false;
    if (t < NBOX) {
        const int* C = counts + ((size_t)b * NBOX + t) * NCLS;
        int c[NCLS];
        #pragma unroll
        for (int i = 0; i < NCLS; ++i) c[i] = C[i];
        int m = c[0]; mj = 0; ssum = c[0];
        #pragma unroll
        for (int i = 1; i < NCLS; ++i) {
            ssum += c[i];
            if (c[i] > m) { m = c[i]; mj = i; }
        }
        pres = ssum > 0;
        int thing = cls[b * NBOX + t] + NSTUFF;
        ts = pres && (mj != thing) && (2 * m >= ssum) && (mj < NSTUFF);
        semv = ts ? mj : thing;
    }
    unsigned long long pm = __ballot(pres);
    idx = __popcll(pm & (((unsigned long long)2 << t) - 1ull)) - 1;
    __syncthreads();

    if (t < NBOX && pres &&  ts) atomicAdd(&l_sh[mj], ssum);
    if (t < NBOX && pres && !ts) { atomicAdd(&l_ih[idx], ssum); l_isem[idx] = semv; }
    __syncthreads();

    bool spres = (t < NSTUFF) && (l_sh[t] > 0);
    unsigned long long sm = __ballot(spres);
    const int nst = __popcll(sm);
    bool ipres = (t < NBOX) && (l_ih[t] > 0);
    unsigned long long im = __ballot(ipres);

    auto srank = [&](int c) { return __popcll(sm & (((unsigned long long)2 << c) - 1ull)) - 1; };
    auto irank = [&](int j) { return __popcll(im & (((unsigned long long)2 << j) - 1ull)) - 1; };

    int* lb = lut + b * (NSTUFF + NBOX);
    if (t < NSTUFF) lb[t] = 1 + srank(t);
    if (t < NBOX) {
        int q = idx < 0 ? 0 : idx;
        lb[NSTUFF + t] = ts ? (1 + srank(mj)) : (1 + nst + irank(q));
    }

    if (spres) l_co[1 + srank(t)] = t;
    if (ipres) l_co[1 + nst + irank(t)] = l_isem[t];
    __syncthreads();

    int* ocls = out + (size_t)BB * NPIX + b * LL;
    int* ocrd = out + (size_t)BB * NPIX + BB * LL + b * LL;
    if (t < LL) { ocls[t] = l_co[t]; ocrd[t] = 0; }
}

// ---------------------------------------------------------------------------
// K3: in-place po_pred -> seam via LUT, int4-vectorized.
// ---------------------------------------------------------------------------
__global__ __launch_bounds__(256) void k_seam(int* __restrict__ out,
                                              const int* __restrict__ lut)
{
    __shared__ int slut[BB * (NSTUFF + NBOX)];
    for (int i = threadIdx.x; i < BB * (NSTUFF + NBOX); i += blockDim.x)
        slut[i] = lut[i];
    __syncthreads();
    const size_t gid = (size_t)blockIdx.x * blockDim.x + threadIdx.x;  // int4 index
    int4 v = ((const int4*)out)[gid];
    const int base = (gid >= (size_t)(NPIX / 4)) ? (NSTUFF + NBOX) : 0;
    v.x = slut[base + v.x];
    v.y = slut[base + v.y];
    v.z = slut[base + v.z];
    v.w = slut[base + v.w];
    ((int4*)out)[gid] = v;
}

extern "C" void kernel_launch(void* const* d_in, const int* in_sizes, int n_in,
                              void* d_out, int out_size, void* d_ws, size_t ws_size,
                              hipStream_t stream) {
    (void)in_sizes; (void)n_in; (void)out_size; (void)ws_size;
    const float* sem = (const float*)d_in[0];
    const float* roi = (const float*)d_in[1];
    const float* bbx = (const float*)d_in[2];
    const int*   cls = (const int*)d_in[3];
    int* out = (int*)d_out;

    int* counts = (int*)d_ws;                        // [B][32][10]
    int* stuffh = counts + BB * NBOX * NCLS;         // [B][6]
    int* lut    = stuffh + BB * NSTUFF;              // [B][38]

    hipMemsetAsync(d_ws, 0, (BB * NBOX * NCLS + BB * NSTUFF) * sizeof(int), stream);

    dim3 g1(NTILES, BB);
    k_fuse<<<g1, 256, 0, stream>>>(sem, roi, bbx, cls, out, counts, stuffh);
    k_label<<<BB, 64, 0, stream>>>(counts, stuffh, cls, out, lut);
    k_seam<<<(BB * NPIX / 4) / 256, 256, 0, stream>>>(out, lut);
}

// Round 4
// 109.977 us; speedup vs baseline: 1.4998x; 1.0799x over previous
//
#include <hip/hip_runtime.h>
#include <math.h>

#define NSTUFF 6
#define NCLS   10          // N_STUFF + N_THING
#define NBOX   32
#define NTHING 4
#define RR     28
#define HH     768
#define WW     704
#define NPIX   (HH * WW)   // 540672
#define BB     2
#define LL     (1 + NSTUFF + NBOX)   // 39
#define NEGV   (-100.0f)

#define TW 64
#define TH 16
#define TILES_X (WW / TW)            // 11
#define TILES_Y (HH / TH)            // 48
#define NTILES  (TILES_X * TILES_Y)  // 528
#define NHIST   (NBOX * NCLS + NSTUFF)

__device__ __forceinline__ float sigmoidf_(float x) {
    return 1.0f / (1.0f + expf(-x));
}

// ---------------------------------------------------------------------------
// K1: tiled fused logits + argmax + histograms. 4 px/thread via float4 sem
// loads (all 10 channels upfront -> one latency round, 16B/lane coalescing).
// Per-tile box cull in-register by wave 0. Sequential-argmax semantics
// preserved via the gap rule (skipped boxes contribute exactly -0.0f; only
// the first box of a skipped run can win, and only while bv < 0).
// ---------------------------------------------------------------------------
__global__ __launch_bounds__(256) void k_fuse(
    const float* __restrict__ sem,   // [B][10][H][W]
    const float* __restrict__ roi,   // [B][32][4][28][28]
    const float* __restrict__ bbx,   // [B][32][4]
    const int*   __restrict__ cls,   // [B][32]
    int*         __restrict__ pred,  // d_out seam region, [B][H][W]
    int*         __restrict__ counts,
    int*         __restrict__ stuffh)
{
    const int b = blockIdx.y;
    __shared__ int   sh_y0[NBOX], sh_x0[NBOX], sh_yme[NBOX], sh_xme[NBOX];
    __shared__ int   sh_yie[NBOX], sh_xie[NBOX], sh_moff[NBOX], sh_cls[NBOX];
    __shared__ float sh_y0f[NBOX], sh_x0f[NBOX], sh_sy[NBOX], sh_sx[NBOX];
    __shared__ int   sh_list[NBOX];
    __shared__ int   sh_nbox;
    __shared__ int   sh_cnt[NHIST];

    const int t = threadIdx.x;
    const int tile = blockIdx.x;
    const int tx0 = (tile % TILES_X) * TW;
    const int ty0 = (tile / TILES_X) * TH;

    const int xq = tx0 + (t & 15) * 4;      // first of this thread's 4 pixels
    const int y  = ty0 + (t >> 4);
    const int p  = y * WW + xq;

    // All 10 channels upfront as float4 (independent loads, one latency round)
    const float* semb = sem + (size_t)b * NCLS * NPIX;
    float4 s4[NCLS];
    #pragma unroll
    for (int c = 0; c < NCLS; ++c)
        s4[c] = *(const float4*)(semb + (size_t)c * NPIX + p);

    for (int i = t; i < NHIST; i += 256) sh_cnt[i] = 0;

    // wave 0: per-box setup + in-register tile cull
    if (t < 64) {
        bool flag = false;
        if (t < NBOX) {
            const float* bbp = bbx + ((size_t)b * NBOX + t) * 4;
            float y0f = bbp[0], x0f = bbp[1], y1f = bbp[2], x1f = bbp[3];
            int y0 = (int)floorf(y0f), x0 = (int)floorf(x0f);
            int y1 = (int)floorf(y1f), x1 = (int)floorf(x1f);
            int yme = min(y1 + 1, HH), xme = min(x1 + 1, WW);
            int yie = (int)rintf(y1f) + 1, xie = (int)rintf(x1f) + 1;
            sh_y0[t] = y0;  sh_x0[t] = x0;
            sh_yme[t] = yme; sh_xme[t] = xme;
            sh_yie[t] = yie; sh_xie[t] = xie;
            sh_y0f[t] = (float)y0; sh_x0f[t] = (float)x0;
            float hh = (float)max(y1 - y0 + 1, 1);
            float ww = (float)max(x1 - x0 + 1, 1);
            sh_sy[t] = 28.0f / hh;  sh_sx[t] = 28.0f / ww;
            int c = cls[b * NBOX + t];
            sh_cls[t] = c;
            sh_moff[t] = (((b * NBOX + t) * NTHING) + c) * (RR * RR);
            int uy = max(yme, yie), ux = max(xme, xie);
            flag = (y0 < ty0 + TH) && (uy > ty0) && (x0 < tx0 + TW) && (ux > tx0);
        }
        unsigned long long m = __ballot(flag);
        if (flag) {
            int pos = __popcll(m & (((unsigned long long)1 << t) - 1ull));
            sh_list[pos] = t;
        }
        if (t == 0) sh_nbox = __popcll(m);
    }
    __syncthreads();

    const int nb = sh_nbox;

    auto doPix = [&](const float* s, int y_, int x_, int& bi_o, int& sp_o) {
        const float yf = (float)y_, xf = (float)x_;
        // sem_pred: full 10-channel argmax, first-occurrence ties
        float sb = s[0]; int sp = 0;
        #pragma unroll
        for (int c = 1; c < NCLS; ++c) if (s[c] > sb) { sb = s[c]; sp = c; }

        // stuff argmax
        float bv = s[0]; int bi = 0;
        #pragma unroll
        for (int c = 1; c < NSTUFF; ++c) if (s[c] > bv) { bv = s[c]; bi = c; }

        int prev = -1;
        for (int j = 0; j < nb; ++j) {
            const int n = sh_list[j];
            if (n > prev + 1 && bv < 0.0f) { bv = -0.0f; bi = NSTUFF + prev + 1; }
            const bool in_m = (y_ >= max(sh_y0[n], 0)) & (y_ < sh_yme[n]) &
                              (x_ >= max(sh_x0[n], 0)) & (x_ < sh_xme[n]);
            const bool in_i = (y_ >= sh_y0[n]) & (y_ < sh_yie[n]) &
                              (x_ >= sh_x0[n]) & (x_ < sh_xie[n]);
            float v;
            if (in_m | in_i) {
                float pm = NEGV;
                if (in_m) {
                    float sy = __fsub_rn(__fmul_rn(__fadd_rn(__fsub_rn(yf, sh_y0f[n]), 0.5f), sh_sy[n]), 0.5f);
                    sy = fminf(fmaxf(sy, 0.0f), 27.0f);
                    int ylo = (int)sy;
                    int yhi = min(ylo + 1, RR - 1);
                    float wy = __fsub_rn(sy, (float)ylo);
                    float sx = __fsub_rn(__fmul_rn(__fadd_rn(__fsub_rn(xf, sh_x0f[n]), 0.5f), sh_sx[n]), 0.5f);
                    sx = fminf(fmaxf(sx, 0.0f), 27.0f);
                    int xlo = (int)sx;
                    int xhi = min(xlo + 1, RR - 1);
                    float wx = __fsub_rn(sx, (float)xlo);
                    const float* m = roi + sh_moff[n];
                    float m00 = m[ylo * RR + xlo], m01 = m[ylo * RR + xhi];
                    float m10 = m[yhi * RR + xlo], m11 = m[yhi * RR + xhi];
                    float omy = __fsub_rn(1.0f, wy), omx = __fsub_rn(1.0f, wx);
                    float rl = __fadd_rn(__fmul_rn(m00, omy), __fmul_rn(m10, wy));
                    float rh = __fadd_rn(__fmul_rn(m01, omy), __fmul_rn(m11, wy));
                    pm = __fadd_rn(__fmul_rn(rl, omx), __fmul_rn(rh, wx));
                }
                float pi = NEGV;
                if (in_i) {
                    int c = sh_cls[n];
                    pi = (c == 0) ? s[6] : (c == 1) ? s[7] : (c == 2) ? s[8] : s[9];
                }
                v = __fmul_rn(__fadd_rn(sigmoidf_(pi), sigmoidf_(pm)), __fadd_rn(pi, pm));
            } else {
                v = -0.0f;
            }
            if (v > bv) { bv = v; bi = NSTUFF + n; }
            prev = n;
        }
        if (prev < NBOX - 1 && bv < 0.0f) { bi = NSTUFF + prev + 1; }
        bi_o = bi; sp_o = sp;
    };

    int bis[4], sps[4];
    #pragma unroll
    for (int j = 0; j < 4; ++j) {
        float s[NCLS];
        #pragma unroll
        for (int c = 0; c < NCLS; ++c) s[c] = ((const float*)&s4[c])[j];
        doPix(s, y, xq + j, bis[j], sps[j]);
    }

    int4 pv; pv.x = bis[0]; pv.y = bis[1]; pv.z = bis[2]; pv.w = bis[3];
    *(int4*)(pred + (size_t)b * NPIX + p) = pv;

    // histogram: ballot-aggregate stuff bins; scatter-atomic instance pixels
    const int lane = t & 63;
    #pragma unroll
    for (int s = 0; s < NSTUFF; ++s) {
        int c = 0;
        #pragma unroll
        for (int j = 0; j < 4; ++j) c += __popcll(__ballot(bis[j] == s));
        if (lane == 0 && c) atomicAdd(&sh_cnt[NBOX * NCLS + s], c);
    }
    #pragma unroll
    for (int j = 0; j < 4; ++j)
        if (bis[j] >= NSTUFF) atomicAdd(&sh_cnt[(bis[j] - NSTUFF) * NCLS + sps[j]], 1);

    __syncthreads();
    for (int i = t; i < NHIST; i += 256) {
        int v = sh_cnt[i];
        if (v) {
            if (i < NBOX * NCLS) atomicAdd(&counts[b * NBOX * NCLS + i], v);
            else                 atomicAdd(&stuffh[b * NSTUFF + (i - NBOX * NCLS)], v);
        }
    }
}

// ---------------------------------------------------------------------------
// K2: fused label + seam remap. Every block recomputes the 38-entry LUT from
// counts/stuffh in wave 0 (~1.3 KB, parallel across blocks; ranks are pure
// functions of ballot masks), then remaps its int4 chunk of pred in place.
// Block (0,b) also writes po_cls / po_iscrowd.
// ---------------------------------------------------------------------------
__global__ __launch_bounds__(256) void k_relabel(
    const int* __restrict__ counts,
    const int* __restrict__ stuffh,
    const int* __restrict__ cls,
    int*       __restrict__ out)
{
    const int b = blockIdx.y;
    const int t = threadIdx.x;
    __shared__ int slut[NSTUFF + NBOX];
    __shared__ int l_sh[NSTUFF];
    __shared__ int l_ih[NBOX];
    __shared__ int l_isem[NBOX];
    __shared__ int l_co[LL];

    int  ssum = 0, mj = 0, semv = 0, idx = -1;
    bool pres = false, ts = false;

    if (t < 64) {
        if (t < NSTUFF) l_sh[t] = stuffh[b * NSTUFF + t];
        if (t < NBOX)  { l_ih[t] = 0; l_isem[t] = 255; }
        if (t < LL)      l_co[t] = 255;

        if (t < NBOX) {
            const int* C = counts + ((size_t)b * NBOX + t) * NCLS;
            int c[NCLS];
            #pragma unroll
            for (int i = 0; i < NCLS; ++i) c[i] = C[i];
            int m = c[0]; mj = 0; ssum = c[0];
            #pragma unroll
            for (int i = 1; i < NCLS; ++i) {
                ssum += c[i];
                if (c[i] > m) { m = c[i]; mj = i; }
            }
            pres = ssum > 0;
            int thing = cls[b * NBOX + t] + NSTUFF;
            ts = pres && (mj != thing) && (2 * m >= ssum) && (mj < NSTUFF);
            semv = ts ? mj : thing;
        }
        unsigned long long pm = __ballot(pres);
        idx = __popcll(pm & (((unsigned long long)2 << t) - 1ull)) - 1;

        if (t < NBOX && pres &&  ts) atomicAdd(&l_sh[mj], ssum);
        if (t < NBOX && pres && !ts) { atomicAdd(&l_ih[idx], ssum); l_isem[idx] = semv; }
    }
    __syncthreads();

    if (t < 64) {
        bool spres = (t < NSTUFF) && (l_sh[t] > 0);
        unsigned long long sm = __ballot(spres);
        const int nst = __popcll(sm);
        bool ipres = (t < NBOX) && (l_ih[t] > 0);
        unsigned long long im = __ballot(ipres);

        auto srank = [&](int c) { return __popcll(sm & (((unsigned long long)2 << c) - 1ull)) - 1; };
        auto irank = [&](int j) { return __popcll(im & (((unsigned long long)2 << j) - 1ull)) - 1; };

        if (t < NSTUFF) slut[t] = 1 + srank(t);
        if (t < NBOX) {
            int q = idx < 0 ? 0 : idx;
            slut[NSTUFF + t] = ts ? (1 + srank(mj)) : (1 + nst + irank(q));
        }
        if (spres) l_co[1 + srank(t)] = t;
        if (ipres) l_co[1 + nst + irank(t)] = l_isem[t];
    }
    __syncthreads();

    // remap this block's int4 chunk of pred in place
    const size_t gi = (size_t)b * (NPIX / 4) + (size_t)blockIdx.x * 256 + t;
    int4 v = ((const int4*)out)[gi];
    v.x = slut[v.x];
    v.y = slut[v.y];
    v.z = slut[v.z];
    v.w = slut[v.w];
    ((int4*)out)[gi] = v;

    if (blockIdx.x == 0 && t < LL) {
        int* ocls = out + (size_t)BB * NPIX + b * LL;
        int* ocrd = out + (size_t)BB * NPIX + BB * LL + b * LL;
        ocls[t] = l_co[t];
        ocrd[t] = 0;
    }
}

extern "C" void kernel_launch(void* const* d_in, const int* in_sizes, int n_in,
                              void* d_out, int out_size, void* d_ws, size_t ws_size,
                              hipStream_t stream) {
    (void)in_sizes; (void)n_in; (void)out_size; (void)ws_size;
    const float* sem = (const float*)d_in[0];
    const float* roi = (const float*)d_in[1];
    const float* bbx = (const float*)d_in[2];
    const int*   cls = (const int*)d_in[3];
    int* out = (int*)d_out;

    int* counts = (int*)d_ws;                        // [B][32][10]
    int* stuffh = counts + BB * NBOX * NCLS;         // [B][6]

    hipMemsetAsync(d_ws, 0, (BB * NBOX * NCLS + BB * NSTUFF) * sizeof(int), stream);

    dim3 g1(NTILES, BB);
    k_fuse<<<g1, 256, 0, stream>>>(sem, roi, bbx, cls, out, counts, stuffh);
    dim3 g2(NPIX / 1024, BB);   // 528 blocks/batch, 256 thr x int4
    k_relabel<<<g2, 256, 0, stream>>>(counts, stuffh, cls, out);
}

// Round 6
// 109.638 us; speedup vs baseline: 1.5044x; 1.0031x over previous
//
#include <hip/hip_runtime.h>
#include <math.h>

#define NSTUFF 6
#define NCLS   10          // N_STUFF + N_THING
#define NBOX   32
#define NTHING 4
#define RR     28
#define HH     768
#define WW     704
#define NPIX   (HH * WW)   // 540672
#define BB     2
#define LL     (1 + NSTUFF + NBOX)   // 39
#define NEGV   (-100.0f)

#define TW 64
#define TH 16
#define TILES_X (WW / TW)            // 11
#define TILES_Y (HH / TH)            // 48
#define NTILES  (TILES_X * TILES_Y)  // 528 per batch
#define NHIST   (NBOX * NCLS + NSTUFF)

__device__ __forceinline__ float sigmoidf_(float x) {
    return 1.0f / (1.0f + expf(-x));
}

// ---------------------------------------------------------------------------
// K1: tiled fused logits + argmax + histograms. 4 px/thread via float4 sem
// loads (all 10 channels upfront -> one latency round). Per-tile box cull
// in-register by wave 0. Winner index (0..37) stored as uchar4 into ws.
// Sequential-argmax semantics preserved via the gap rule (skipped boxes
// contribute exactly -0.0f; only the first box of a skipped run can win, and
// only while bv < 0).
// ---------------------------------------------------------------------------
__global__ __launch_bounds__(256) void k_fuse(
    const float* __restrict__ sem,   // [B][10][H][W]
    const float* __restrict__ roi,   // [B][32][4][28][28]
    const float* __restrict__ bbx,   // [B][32][4]
    const int*   __restrict__ cls,   // [B][32]
    uchar4*      __restrict__ pred8, // ws region, [B][H][W] bytes as uchar4
    int*         __restrict__ counts,
    int*         __restrict__ stuffh)
{
    const int b = blockIdx.y;
    __shared__ int   sh_y0[NBOX], sh_x0[NBOX], sh_yme[NBOX], sh_xme[NBOX];
    __shared__ int   sh_yie[NBOX], sh_xie[NBOX], sh_moff[NBOX], sh_cls[NBOX];
    __shared__ float sh_y0f[NBOX], sh_x0f[NBOX], sh_sy[NBOX], sh_sx[NBOX];
    __shared__ int   sh_list[NBOX];
    __shared__ int   sh_nbox;
    __shared__ int   sh_cnt[NHIST];

    const int t = threadIdx.x;
    const int tile = blockIdx.x;
    const int tx0 = (tile % TILES_X) * TW;
    const int ty0 = (tile / TILES_X) * TH;

    const int xq = tx0 + (t & 15) * 4;      // first of this thread's 4 pixels
    const int y  = ty0 + (t >> 4);
    const int p  = y * WW + xq;

    // All 10 channels upfront as float4 (independent loads, one latency round)
    const float* semb = sem + (size_t)b * NCLS * NPIX;
    float4 s4[NCLS];
    #pragma unroll
    for (int c = 0; c < NCLS; ++c)
        s4[c] = *(const float4*)(semb + (size_t)c * NPIX + p);

    for (int i = t; i < NHIST; i += 256) sh_cnt[i] = 0;

    // wave 0: per-box setup + in-register tile cull
    if (t < 64) {
        bool flag = false;
        if (t < NBOX) {
            const float* bbp = bbx + ((size_t)b * NBOX + t) * 4;
            float y0f = bbp[0], x0f = bbp[1], y1f = bbp[2], x1f = bbp[3];
            int y0 = (int)floorf(y0f), x0 = (int)floorf(x0f);
            int y1 = (int)floorf(y1f), x1 = (int)floorf(x1f);
            int yme = min(y1 + 1, HH), xme = min(x1 + 1, WW);
            int yie = (int)rintf(y1f) + 1, xie = (int)rintf(x1f) + 1;
            sh_y0[t] = y0;  sh_x0[t] = x0;
            sh_yme[t] = yme; sh_xme[t] = xme;
            sh_yie[t] = yie; sh_xie[t] = xie;
            sh_y0f[t] = (float)y0; sh_x0f[t] = (float)x0;
            float hh = (float)max(y1 - y0 + 1, 1);
            float ww = (float)max(x1 - x0 + 1, 1);
            sh_sy[t] = 28.0f / hh;  sh_sx[t] = 28.0f / ww;
            int c = cls[b * NBOX + t];
            sh_cls[t] = c;
            sh_moff[t] = (((b * NBOX + t) * NTHING) + c) * (RR * RR);
            int uy = max(yme, yie), ux = max(xme, xie);
            flag = (y0 < ty0 + TH) && (uy > ty0) && (x0 < tx0 + TW) && (ux > tx0);
        }
        unsigned long long m = __ballot(flag);
        if (flag) {
            int pos = __popcll(m & (((unsigned long long)1 << t) - 1ull));
            sh_list[pos] = t;
        }
        if (t == 0) sh_nbox = __popcll(m);
    }
    __syncthreads();

    const int nb = sh_nbox;

    auto doPix = [&](const float* s, int y_, int x_, int& bi_o, int& sp_o) {
        const float yf = (float)y_, xf = (float)x_;
        // sem_pred: full 10-channel argmax, first-occurrence ties
        float sb = s[0]; int sp = 0;
        #pragma unroll
        for (int c = 1; c < NCLS; ++c) if (s[c] > sb) { sb = s[c]; sp = c; }

        // stuff argmax
        float bv = s[0]; int bi = 0;
        #pragma unroll
        for (int c = 1; c < NSTUFF; ++c) if (s[c] > bv) { bv = s[c]; bi = c; }

        int prev = -1;
        for (int j = 0; j < nb; ++j) {
            const int n = sh_list[j];
            if (n > prev + 1 && bv < 0.0f) { bv = -0.0f; bi = NSTUFF + prev + 1; }
            const bool in_m = (y_ >= max(sh_y0[n], 0)) & (y_ < sh_yme[n]) &
                              (x_ >= max(sh_x0[n], 0)) & (x_ < sh_xme[n]);
            const bool in_i = (y_ >= sh_y0[n]) & (y_ < sh_yie[n]) &
                              (x_ >= sh_x0[n]) & (x_ < sh_xie[n]);
            float v;
            if (in_m | in_i) {
                float pm = NEGV;
                if (in_m) {
                    float sy = __fsub_rn(__fmul_rn(__fadd_rn(__fsub_rn(yf, sh_y0f[n]), 0.5f), sh_sy[n]), 0.5f);
                    sy = fminf(fmaxf(sy, 0.0f), 27.0f);
                    int ylo = (int)sy;
                    int yhi = min(ylo + 1, RR - 1);
                    float wy = __fsub_rn(sy, (float)ylo);
                    float sx = __fsub_rn(__fmul_rn(__fadd_rn(__fsub_rn(xf, sh_x0f[n]), 0.5f), sh_sx[n]), 0.5f);
                    sx = fminf(fmaxf(sx, 0.0f), 27.0f);
                    int xlo = (int)sx;
                    int xhi = min(xlo + 1, RR - 1);
                    float wx = __fsub_rn(sx, (float)xlo);
                    const float* m = roi + sh_moff[n];
                    float m00 = m[ylo * RR + xlo], m01 = m[ylo * RR + xhi];
                    float m10 = m[yhi * RR + xlo], m11 = m[yhi * RR + xhi];
                    float omy = __fsub_rn(1.0f, wy), omx = __fsub_rn(1.0f, wx);
                    float rl = __fadd_rn(__fmul_rn(m00, omy), __fmul_rn(m10, wy));
                    float rh = __fadd_rn(__fmul_rn(m01, omy), __fmul_rn(m11, wy));
                    pm = __fadd_rn(__fmul_rn(rl, omx), __fmul_rn(rh, wx));
                }
                float pi = NEGV;
                if (in_i) {
                    int c = sh_cls[n];
                    pi = (c == 0) ? s[6] : (c == 1) ? s[7] : (c == 2) ? s[8] : s[9];
                }
                v = __fmul_rn(__fadd_rn(sigmoidf_(pi), sigmoidf_(pm)), __fadd_rn(pi, pm));
            } else {
                v = -0.0f;
            }
            if (v > bv) { bv = v; bi = NSTUFF + n; }
            prev = n;
        }
        if (prev < NBOX - 1 && bv < 0.0f) { bi = NSTUFF + prev + 1; }
        bi_o = bi; sp_o = sp;
    };

    int bis[4], sps[4];
    #pragma unroll
    for (int j = 0; j < 4; ++j) {
        float s[NCLS];
        #pragma unroll
        for (int c = 0; c < NCLS; ++c) s[c] = ((const float*)&s4[c])[j];
        doPix(s, y, xq + j, bis[j], sps[j]);
    }

    uchar4 pv;
    pv.x = (unsigned char)bis[0]; pv.y = (unsigned char)bis[1];
    pv.z = (unsigned char)bis[2]; pv.w = (unsigned char)bis[3];
    pred8[((size_t)b * NPIX + p) >> 2] = pv;

    // histogram: ballot-aggregate stuff bins; scatter-atomic instance pixels
    const int lane = t & 63;
    #pragma unroll
    for (int s = 0; s < NSTUFF; ++s) {
        int c = 0;
        #pragma unroll
        for (int j = 0; j < 4; ++j) c += __popcll(__ballot(bis[j] == s));
        if (lane == 0 && c) atomicAdd(&sh_cnt[NBOX * NCLS + s], c);
    }
    #pragma unroll
    for (int j = 0; j < 4; ++j)
        if (bis[j] >= NSTUFF) atomicAdd(&sh_cnt[(bis[j] - NSTUFF) * NCLS + sps[j]], 1);

    __syncthreads();
    for (int i = t; i < NHIST; i += 256) {
        int v = sh_cnt[i];
        if (v) {
            if (i < NBOX * NCLS) atomicAdd(&counts[b * NBOX * NCLS + i], v);
            else                 atomicAdd(&stuffh[b * NSTUFF + (i - NBOX * NCLS)], v);
        }
    }
}

// ---------------------------------------------------------------------------
// K2: fused label + seam remap. Pred bytes are loaded BEFORE the LUT barrier
// (independent of it) so wave-0's LUT recompute latency is hidden behind the
// global load. Ranks are pure functions of ballot masks. Block (0,b) also
// writes po_cls / po_iscrowd.
// ---------------------------------------------------------------------------
__global__ __launch_bounds__(256) void k_relabel(
    const int*    __restrict__ counts,
    const int*    __restrict__ stuffh,
    const int*    __restrict__ cls,
    const uchar4* __restrict__ pred8,
    int*          __restrict__ out)
{
    const int b = blockIdx.y;
    const int t = threadIdx.x;
    __shared__ int slut[NSTUFF + NBOX];
    __shared__ int l_sh[NSTUFF];
    __shared__ int l_ih[NBOX];
    __shared__ int l_isem[NBOX];
    __shared__ int l_co[LL];

    // issue the pred load first (independent of the LUT)
    const size_t q = (size_t)b * (NPIX / 4) + (size_t)blockIdx.x * 256 + t;
    const uchar4 v = pred8[q];

    int  ssum = 0, mj = 0, semv = 0, idx = -1;
    bool pres = false, ts = false;

    if (t < 64) {
        if (t < NSTUFF) l_sh[t] = stuffh[b * NSTUFF + t];
        if (t < NBOX)  { l_ih[t] = 0; l_isem[t] = 255; }
        if (t < LL)      l_co[t] = 255;

        if (t < NBOX) {
            const int* C = counts + ((size_t)b * NBOX + t) * NCLS;
            int c[NCLS];
            #pragma unroll
            for (int i = 0; i < NCLS; ++i) c[i] = C[i];
            int m = c[0]; mj = 0; ssum = c[0];
            #pragma unroll
            for (int i = 1; i < NCLS; ++i) {
                ssum += c[i];
                if (c[i] > m) { m = c[i]; mj = i; }
            }
            pres = ssum > 0;
            int thing = cls[b * NBOX + t] + NSTUFF;
            ts = pres && (mj != thing) && (2 * m >= ssum) && (mj < NSTUFF);
            semv = ts ? mj : thing;
        }
        unsigned long long pm = __ballot(pres);
        idx = __popcll(pm & (((unsigned long long)2 << t) - 1ull)) - 1;

        if (t < NBOX && pres &&  ts) atomicAdd(&l_sh[mj], ssum);
        if (t < NBOX && pres && !ts) { atomicAdd(&l_ih[idx], ssum); l_isem[idx] = semv; }
    }
    __syncthreads();

    if (t < 64) {
        bool spres = (t < NSTUFF) && (l_sh[t] > 0);
        unsigned long long sm = __ballot(spres);
        const int nst = __popcll(sm);
        bool ipres = (t < NBOX) && (l_ih[t] > 0);
        unsigned long long im = __ballot(ipres);

        auto srank = [&](int c) { return __popcll(sm & (((unsigned long long)2 << c) - 1ull)) - 1; };
        auto irank = [&](int j) { return __popcll(im & (((unsigned long long)2 << j) - 1ull)) - 1; };

        if (t < NSTUFF) slut[t] = 1 + srank(t);
        if (t < NBOX) {
            int q2 = idx < 0 ? 0 : idx;
            slut[NSTUFF + t] = ts ? (1 + srank(mj)) : (1 + nst + irank(q2));
        }
        if (spres) l_co[1 + srank(t)] = t;
        if (ipres) l_co[1 + nst + irank(t)] = l_isem[t];
    }
    __syncthreads();

    int4 o;
    o.x = slut[v.x];
    o.y = slut[v.y];
    o.z = slut[v.z];
    o.w = slut[v.w];
    ((int4*)out)[q] = o;

    if (blockIdx.x == 0 && t < LL) {
        int* ocls = out + (size_t)BB * NPIX + b * LL;
        int* ocrd = out + (size_t)BB * NPIX + BB * LL + b * LL;
        ocls[t] = l_co[t];
        ocrd[t] = 0;
    }
}

extern "C" void kernel_launch(void* const* d_in, const int* in_sizes, int n_in,
                              void* d_out, int out_size, void* d_ws, size_t ws_size,
                              hipStream_t stream) {
    (void)in_sizes; (void)n_in; (void)out_size; (void)ws_size;
    const float* sem = (const float*)d_in[0];
    const float* roi = (const float*)d_in[1];
    const float* bbx = (const float*)d_in[2];
    const int*   cls = (const int*)d_in[3];
    int* out = (int*)d_out;

    int* counts = (int*)d_ws;                        // [B][32][10]
    int* stuffh = counts + BB * NBOX * NCLS;         // [B][6]
    // 652 ints = 2608 B (16B-aligned); pred bytes follow
    uchar4* pred8 = (uchar4*)(stuffh + BB * NSTUFF); // [B*NPIX] bytes

    hipMemsetAsync(d_ws, 0, (BB * NBOX * NCLS + BB * NSTUFF) * sizeof(int), stream);

    dim3 g1(NTILES, BB);
    k_fuse<<<g1, 256, 0, stream>>>(sem, roi, bbx, cls, pred8, counts, stuffh);
    dim3 g2(NPIX / 1024, BB);   // 528 blocks/batch, 256 thr x 4 px
    k_relabel<<<g2, 256, 0, stream>>>(counts, stuffh, cls, pred8, out);
}